// Round 1
// baseline (127.121 us; speedup 1.0000x reference)
//
#include <hip/hip_runtime.h>

// norm_conv: im2col(3x3 reflect) -> row-normalize -> GEMM[576x64], fused.
// Design: out = (patches@W - mean*colsum(W)) * inv_std.
//  - kernel 1: pre-pack W (fp32->bf16) into per-lane MFMA B-fragment layout in ws.
//  - kernel 2: 512 blocks (one half-image each), 256 thr, 2 blocks/CU.
//    Stage 17 rows x 32 cols x 64ch as bf16 in LDS [pixel][channel] (stride 68
//    ushorts = 136B = 34 banks -> 2-way-only conflicts). K reordered to
//    (spatial-offset major, channel minor) so A-frag = 8 consecutive channels
//    = 2x ds_read_b64. B frags live in 144 VGPRs per wave.

#define STRIDE 68            // ushorts per pixel in LDS (136 B)
#define NPIX   544           // 17 rows x 32 cols

typedef __attribute__((ext_vector_type(8))) short bf16x8;
typedef __attribute__((ext_vector_type(4))) short bf16x4;
typedef __attribute__((ext_vector_type(4))) float f32x4;

__device__ __forceinline__ unsigned short f2bf(float f) {
    union { float f; unsigned u; } v; v.f = f;
    unsigned r = v.u + 0x7FFFu + ((v.u >> 16) & 1u);   // RNE
    return (unsigned short)(r >> 16);
}

__device__ __forceinline__ int reflect32(int x) {      // jnp.pad 'reflect', pad=1
    x = (x < 0) ? -x : x;
    return (x > 31) ? (62 - x) : x;
}

// ws layout: uint4 wf[4][18][64]  (ntg, ks, lane) -> 8 bf16 B-frag elements.
// B[k'][o]: o = ntg*16 + (lane&15), k' = ks*32 + (lane>>4)*8 + j,
// with reordered k' = (kh*3+kw)*64 + c  <->  reference k = c*9 + (kh*3+kw).
__global__ void reorder_w_kernel(const float* __restrict__ W, uint4* __restrict__ wf) {
    int idx = blockIdx.x * 256 + threadIdx.x;   // 0..4607
    if (idx >= 4608) return;
    int lane = idx & 63;
    int ks   = (idx >> 6) % 18;
    int ntg  = idx / 1152;
    int quad = lane >> 4;
    int o    = ntg * 16 + (lane & 15);
    unsigned short v[8];
    #pragma unroll
    for (int j = 0; j < 8; ++j) {
        int kp = ks * 32 + quad * 8 + j;
        int c  = kp & 63;
        int s  = kp >> 6;
        v[j] = f2bf(W[(c * 9 + s) * 64 + o]);
    }
    uint4 r;
    r.x = (unsigned)v[0] | ((unsigned)v[1] << 16);
    r.y = (unsigned)v[2] | ((unsigned)v[3] << 16);
    r.z = (unsigned)v[4] | ((unsigned)v[5] << 16);
    r.w = (unsigned)v[6] | ((unsigned)v[7] << 16);
    wf[idx] = r;
}

__global__ __launch_bounds__(256, 2)
void norm_conv_kernel(const float* __restrict__ a,
                      const uint4* __restrict__ wf,
                      float* __restrict__ out) {
    __shared__ unsigned short img[NPIX * STRIDE];   // 73,984 B
    __shared__ float sums[1088];                    // csum[544] | cssq[544]; later (mean,inv)[512] pairs

    const int tid  = threadIdx.x;
    const int b    = blockIdx.x >> 1;
    const int half = blockIdx.x & 1;        // 0: out rows 0-15 (store rows 0-16); 1: rows 16-31 (store 15-31)
    const int row_base = half * 15;
    const int lane = tid & 63;
    const int wid  = tid >> 6;              // 4 waves
    const int ng   = wid & 1;               // n-half: o in [ng*32, ng*32+32)
    const int wq   = wid >> 1;              // m-half: 16 m-tiles each
    const int quad = lane >> 4;
    const int mlan = lane & 15;

    // ---- B fragments: 2 n-tiles x 18 k-steps, held in registers ----
    bf16x8 bfrag[2][18];
    #pragma unroll
    for (int nt = 0; nt < 2; ++nt) {
        #pragma unroll
        for (int ks = 0; ks < 18; ++ks) {
            union { uint4 u; bf16x8 v; } cvt;
            cvt.u = wf[((ng * 2 + nt) * 18 + ks) * 64 + lane];
            bfrag[nt][ks] = cvt.v;
        }
    }

    // ---- stage half-image to LDS bf16 + fp32 per-pixel channel sums ----
    const float* Ab = a + (size_t)b * 65536 + row_base * 32;
    for (int p = tid; p < NPIX; p += 256) {
        float s = 0.f, q = 0.f;
        unsigned short* row = &img[p * STRIDE];
        #pragma unroll 8
        for (int c = 0; c < 64; c += 2) {
            float v0 = Ab[c * 1024 + p];          // coalesced across lanes (p = lane-consecutive)
            float v1 = Ab[(c + 1) * 1024 + p];
            s += v0 + v1;
            q += v0 * v0 + v1 * v1;
            unsigned pk = (unsigned)f2bf(v0) | ((unsigned)f2bf(v1) << 16);
            *(unsigned*)&row[c] = pk;             // ds_write_b32, 2-way banked
        }
        sums[p] = s;
        sums[NPIX + p] = q;
    }
    __syncthreads();

    // ---- per-output-pixel mean / inv-std via 3x3 box of channel sums ----
    float mean_[2], inv_[2];
    #pragma unroll
    for (int i = 0; i < 2; ++i) {
        int lo = tid + i * 256;                   // 0..511 local output pixel
        int hg = half * 16 + (lo >> 5);
        int wg = lo & 31;
        float s = 0.f, q = 0.f;
        #pragma unroll
        for (int kh = 0; kh < 3; ++kh) {
            int hr = reflect32(hg + kh - 1) - row_base;
            #pragma unroll
            for (int kw = 0; kw < 3; ++kw) {
                int p = hr * 32 + reflect32(wg + kw - 1);
                s += sums[p];
                q += sums[NPIX + p];
            }
        }
        float mean = s * (1.0f / 576.0f);
        float var  = (q - s * mean) * (1.0f / 575.0f);   // ddof=1
        mean_[i] = mean;
        inv_[i]  = rsqrtf(var);
    }
    __syncthreads();
    #pragma unroll
    for (int i = 0; i < 2; ++i) {
        int lo = tid + i * 256;
        sums[lo * 2]     = mean_[i];              // overlay (mean,inv) pairs
        sums[lo * 2 + 1] = inv_[i];
    }
    __syncthreads();

    // ---- colsum(W_bf16) per lane's two o-columns (exact vs the bf16 GEMM) ----
    float So[2];
    #pragma unroll
    for (int nt = 0; nt < 2; ++nt) {
        float s = 0.f;
        #pragma unroll
        for (int ks = 0; ks < 18; ++ks) {
            #pragma unroll
            for (int j = 0; j < 8; ++j) {
                union { unsigned u; float f; } cv;
                cv.u = ((unsigned)(unsigned short)bfrag[nt][ks][j]) << 16;
                s += cv.f;
            }
        }
        s += __shfl_xor(s, 16, 64);               // sum quads: each quad holds k' subset
        s += __shfl_xor(s, 32, 64);
        So[nt] = s;
    }

    // ---- main loop: 16 m-tiles of 16 pixels, K=576 as 18 MFMA k-steps ----
    float* outB = out + (size_t)b * 65536 + half * 512;
    const char* imgc = (const char*)img;
    for (int i = 0; i < 16; ++i) {
        int mt = wq * 16 + i;
        int hg = half * 16 + (mt >> 1);
        int wl = ((mt & 1) << 4) + mlan;          // this lane's w (A-operand m = lane&15)
        int base9[9];                             // byte offset per (kh,kw), const-indexed -> regs
        #pragma unroll
        for (int kh = 0; kh < 3; ++kh) {
            int pr = (reflect32(hg + kh - 1) - row_base) * 32;
            #pragma unroll
            for (int kw = 0; kw < 3; ++kw) {
                base9[kh * 3 + kw] = ((pr + reflect32(wl + kw - 1)) * STRIDE + quad * 8) * 2;
            }
        }
        f32x4 acc0 = {0.f, 0.f, 0.f, 0.f};
        f32x4 acc1 = {0.f, 0.f, 0.f, 0.f};
        #pragma unroll
        for (int ks = 0; ks < 18; ++ks) {
            int off = base9[ks >> 1] + (ks & 1) * 64;           // +32 channels on odd ks
            bf16x4 flo = *(const bf16x4*)(imgc + off);          // ds_read_b64 x2 (8B aligned)
            bf16x4 fhi = *(const bf16x4*)(imgc + off + 8);
            bf16x8 af  = __builtin_shufflevector(flo, fhi, 0, 1, 2, 3, 4, 5, 6, 7);
            acc0 = __builtin_amdgcn_mfma_f32_16x16x32_bf16(af, bfrag[0][ks], acc0, 0, 0, 0);
            acc1 = __builtin_amdgcn_mfma_f32_16x16x32_bf16(af, bfrag[1][ks], acc1, 0, 0, 0);
        }
        // epilogue: D row = quad*4+reg (spatial), col = lane&15 (out channel)
        int l0 = mt * 16 + quad * 4;
        f32x4 r0, r1;
        #pragma unroll
        for (int r = 0; r < 4; ++r) {
            float mean = sums[(l0 + r) * 2];
            float inv  = sums[(l0 + r) * 2 + 1];
            r0[r] = (acc0[r] - mean * So[0]) * inv;
            r1[r] = (acc1[r] - mean * So[1]) * inv;
        }
        int o0 = ng * 32 + mlan;
        *(f32x4*)(outB + o0 * 1024 + l0) = r0;
        *(f32x4*)(outB + (o0 + 16) * 1024 + l0) = r1;
    }
}

extern "C" void kernel_launch(void* const* d_in, const int* in_sizes, int n_in,
                              void* d_out, int out_size, void* d_ws, size_t ws_size,
                              hipStream_t stream) {
    const float* a = (const float*)d_in[0];
    const float* w = (const float*)d_in[1];
    float* out = (float*)d_out;
    uint4* wf = (uint4*)d_ws;                      // needs 4608*16 = 73,728 B
    reorder_w_kernel<<<dim3(18), dim3(256), 0, stream>>>(w, wf);
    norm_conv_kernel<<<dim3(512), dim3(256), 0, stream>>>(a, (const uint4*)wf, out);
}